// Round 14
// baseline (175.234 us; speedup 1.0000x reference)
//
#include <hip/hip_runtime.h>

// ---------------- problem constants ----------------
// B*P=32, N=512, D=128, H=4, DK=32, T=3 (tm {0,1,3}; tsel(t)=t+(t>>1))
// Inputs f32, OUTPUT f32. XL path (ws >= 54.9MB) confirmed.
// R13: 171.4us; attn2 56.4us at zero fetch redundancy (proven floor-ish).
// R14: kill the Xb round-trip (24MB HBM): prep converts only W/Wo (tiny);
// k_qkv_x stages X inline (R12-proven cvt) with grid x=t so the 3 blocks
// sharing an X tile are dispatch-adjacent (L2-hot). attn2/oproj unchanged.

typedef __attribute__((ext_vector_type(8))) short  short8;
typedef __attribute__((ext_vector_type(4))) float  floatx4;

#define WS_BIG   50331648ull                  // q3/k3/v3 (37.7MB) + att (12.6MB)
#define WS_XL    54919168ull                  // + Wb 288KB + Wob 96KB (tail kept for layout compat)
#define QSCALE   0.25503486f                  // (1/sqrt(32)) * log2(e)

__device__ __forceinline__ float b2f(unsigned short u) {
    union { unsigned int i; float f; } v; v.i = ((unsigned int)u) << 16; return v.f;
}
__device__ __forceinline__ unsigned short f2b(float f) {
    union { float f; unsigned int i; } v; v.f = f;
    unsigned int x = v.i;
    return (unsigned short)((x + 0x7fffu + ((x >> 16) & 1u)) >> 16);
}
__device__ __forceinline__ unsigned int fbits(float f) {
    union { float f; unsigned int i; } v; v.f = f; return v.i;
}
__device__ __forceinline__ short8 cvt8(const float* p) {
    floatx4 a = *(const floatx4*)p;
    floatx4 b = *(const floatx4*)(p + 4);
    short8 r;
    r[0] = (short)f2b(a[0]); r[1] = (short)f2b(a[1]);
    r[2] = (short)f2b(a[2]); r[3] = (short)f2b(a[3]);
    r[4] = (short)f2b(b[0]); r[5] = (short)f2b(b[1]);
    r[6] = (short)f2b(b[2]); r[7] = (short)f2b(b[3]);
    return r;
}

// ---------------- K0: one-time f32->bf16 of W q/k/v + Wo ONLY (0.4MB) ---------
// grid 96 x 256, 8 elems/thread: Wq/Wk/Wv 49,152 each | Wo 49,152.
__global__ __launch_bounds__(256) void k_prep_w(
    const float* __restrict__ Wq, const float* __restrict__ Wk,
    const float* __restrict__ Wv, const float* __restrict__ Wo,
    unsigned short* __restrict__ Wb, unsigned short* __restrict__ Wob)
{
    size_t i = ((size_t)blockIdx.x * 256 + threadIdx.x) * 8;
    const float* src; unsigned short* dst; size_t off;
    if      (i <  49152) { src = Wq; dst = Wb;          off = i; }
    else if (i <  98304) { src = Wk; dst = Wb + 49152;  off = i - 49152; }
    else if (i < 147456) { src = Wv; dst = Wb + 98304;  off = i - 98304; }
    else                 { src = Wo; dst = Wob;         off = i - 147456; }
    *(short8*)&dst[off] = cvt8(&src[off]);
}

// ---------------- K1a: QKV projection, inline X cvt + L2-friendly grid --------
// grid (x=t 3, y=mt 4, z=bp 32): the 3 t-blocks of one X tile are adjacent in
// dispatch order -> X f32 fetched from HBM once, L2-hot for t=1,2.
// LDS = Xs 32KB + Cs 32KB = 64KB. Cs swizzled repack (R12-proven).
__global__ __launch_bounds__(256) void k_qkv_x(
    const float* __restrict__ X,             // [32][512][128] f32
    const unsigned short* __restrict__ Wb,   // [3 qkv][3 t][128][128] bf16
    unsigned short* __restrict__ q_ws,
    unsigned short* __restrict__ k_ws,
    unsigned short* __restrict__ v_ws)
{
    int t = blockIdx.x, mt = blockIdx.y, bp = blockIdx.z;
    __shared__ unsigned short Xs[128 * 128];     // 32 KB
    __shared__ unsigned short Cs[4][32 * 128];   // 32 KB (8KB per wave)
    int tid = threadIdx.x;
    int lane = tid & 63, wv = tid >> 6;
    int l15 = lane & 15, quad = lane >> 4;

    const float* Xbase = X + ((size_t)bp * 512 + mt * 128) * 128;
    for (int i = 0; i < 8; ++i) {
        int e = (i * 256 + tid) * 8;
        *(short8*)&Xs[e] = cvt8(&Xbase[e]);
    }
    __syncthreads();

    unsigned short* Osel[3] = { q_ws, k_ws, v_ws };
    int rt0 = wv * 2, rt1 = wv * 2 + 1;

    for (int qkv = 0; qkv < 3; ++qkv) {
        const unsigned short* Wt = Wb + qkv * 49152 + t * 16384;
        unsigned short* Ob = Osel[qkv] + (size_t)t * 2097152
                           + ((size_t)bp * 512 + mt * 128 + wv * 32) * 128;
        float sc = (qkv == 0) ? QSCALE : 1.0f;

        for (int ct = 0; ct < 8; ++ct) {
            short8 bfr[4];
            for (int kk = 0; kk < 4; ++kk)
                bfr[kk] = *(const short8*)&Wt[(size_t)(ct * 16 + l15) * 128 + kk * 32 + quad * 8];
            floatx4 acc0 = {0.f, 0.f, 0.f, 0.f};
            floatx4 acc1 = {0.f, 0.f, 0.f, 0.f};
            for (int kk = 0; kk < 4; ++kk) {
                short8 a0 = *(const short8*)&Xs[(rt0 * 16 + l15) * 128 + kk * 32 + quad * 8];
                short8 a1 = *(const short8*)&Xs[(rt1 * 16 + l15) * 128 + kk * 32 + quad * 8];
                acc0 = __builtin_amdgcn_mfma_f32_16x16x32_bf16(a0, bfr[kk], acc0, 0, 0, 0);
                acc1 = __builtin_amdgcn_mfma_f32_16x16x32_bf16(a1, bfr[kk], acc1, 0, 0, 0);
            }
            #pragma unroll
            for (int i = 0; i < 4; ++i) {
                int row = quad * 4 + i;
                int swz = (row & 7) << 4;
                int col = (ct * 16 + l15) ^ swz;
                Cs[wv][row * 128 + col]        = f2b(acc0[i] * sc);
                Cs[wv][(16 + row) * 128 + col] = f2b(acc1[i] * sc);
            }
        }
        #pragma unroll
        for (int j = 0; j < 8; ++j) {
            int flat = j * 64 + lane;
            int r = flat >> 4;
            int cg = (flat & 15) * 8;
            int cgs = cg ^ ((r & 7) << 4);
            *(short8*)&Ob[(size_t)r * 128 + cg] = *(const short8*)&Cs[wv][r * 128 + cgs];
        }
    }
}

// ---------------- K1b: QKV projection, inline-cvt fallback --------------------
__global__ __launch_bounds__(256) void k_qkv_cvt(
    const float* __restrict__ X,
    const float* __restrict__ Wq, const float* __restrict__ Wk,
    const float* __restrict__ Wv,
    unsigned short* __restrict__ q_ws, unsigned short* __restrict__ k_ws,
    unsigned short* __restrict__ v_ws,
    int wstride, int ostride)
{
    int bp = blockIdx.x, mt = blockIdx.y, tz = blockIdx.z;
    __shared__ unsigned short Xs[128 * 128];
    int tid = threadIdx.x;
    int lane = tid & 63, wv = tid >> 6;
    int l15 = lane & 15, quad = lane >> 4;

    const float* Xbase = X + ((size_t)bp * 512 + mt * 128) * 128;
    for (int i = 0; i < 8; ++i) {
        int e = (i * 256 + tid) * 8;
        *(short8*)&Xs[e] = cvt8(&Xbase[e]);
    }
    __syncthreads();

    size_t woff = (size_t)tz * wstride;
    size_t ooff = (size_t)tz * ostride;
    const float* Wsel[3] = { Wq + woff, Wk + woff, Wv + woff };
    unsigned short* Osel[3] = { q_ws + ooff, k_ws + ooff, v_ws + ooff };

    for (int qkv = 0; qkv < 3; ++qkv) {
        const float* Wt = Wsel[qkv];
        unsigned short* Ob = Osel[qkv] + ((size_t)bp * 512 + mt * 128) * 128;
        float sc = (qkv == 0) ? QSCALE : 1.0f;
        for (int ct = 0; ct < 8; ++ct) {
            short8 bfr[4];
            for (int kk = 0; kk < 4; ++kk)
                bfr[kk] = cvt8(&Wt[(size_t)(ct * 16 + l15) * 128 + kk * 32 + quad * 8]);
            floatx4 acc0 = {0.f, 0.f, 0.f, 0.f};
            floatx4 acc1 = {0.f, 0.f, 0.f, 0.f};
            int rt0 = wv * 2, rt1 = wv * 2 + 1;
            for (int kk = 0; kk < 4; ++kk) {
                short8 a0 = *(const short8*)&Xs[(rt0 * 16 + l15) * 128 + kk * 32 + quad * 8];
                short8 a1 = *(const short8*)&Xs[(rt1 * 16 + l15) * 128 + kk * 32 + quad * 8];
                acc0 = __builtin_amdgcn_mfma_f32_16x16x32_bf16(a0, bfr[kk], acc0, 0, 0, 0);
                acc1 = __builtin_amdgcn_mfma_f32_16x16x32_bf16(a1, bfr[kk], acc1, 0, 0, 0);
            }
            int col = ct * 16 + l15;
            for (int i = 0; i < 4; ++i) {
                Ob[(size_t)(rt0 * 16 + quad * 4 + i) * 128 + col] = f2b(acc0[i] * sc);
                Ob[(size_t)(rt1 * 16 + quad * 4 + i) * 128 + col] = f2b(acc1[i] * sc);
            }
        }
    }
}

// ---------------- K2: dense MFMA attention, 2 strips/wave (R13-proven) --------
__global__ __launch_bounds__(512) void k_attn2(
    const unsigned short* __restrict__ q_ws,   // bf16, pre-scaled by QSCALE
    const unsigned short* __restrict__ k_ws,
    const unsigned short* __restrict__ v_ws,
    const float* __restrict__ tm,
    unsigned short* __restrict__ att_ws,       // [32][512][384] bf16
    int qkv_stride, int toff0)
{
    int nc2 = blockIdx.x;
    int bp = blockIdx.y;
    int z  = blockIdx.z;
    int t = z >> 2, h = z & 3;
    size_t qoff = (size_t)t * (size_t)qkv_stride;
    const float* tmt = tm + (size_t)(t + (t >> 1)) * 262144;
    int toff = toff0 + t * 128;

    __shared__ unsigned short Vt[32][516];
    __shared__ unsigned short Ps[8][16][72];

    int tid = threadIdx.x, lane = tid & 63, wv = tid >> 6;
    int l15 = lane & 15, quad = lane >> 4;

    {
        const unsigned short* vp = v_ws + qoff + ((size_t)bp * 512 + tid) * 128 + h * 32;
        short8 a = *(const short8*)vp;
        short8 b = *(const short8*)(vp + 8);
        short8 c = *(const short8*)(vp + 16);
        short8 d = *(const short8*)(vp + 24);
        #pragma unroll
        for (int j = 0; j < 8; ++j) {
            Vt[j][tid]      = (unsigned short)a[j];
            Vt[8 + j][tid]  = (unsigned short)b[j];
            Vt[16 + j][tid] = (unsigned short)c[j];
            Vt[24 + j][tid] = (unsigned short)d[j];
        }
    }
    int n0 = nc2 * 256 + wv * 16;
    short8 qf[2];
    qf[0] = *(const short8*)&q_ws[qoff +
        ((size_t)bp * 512 + n0 + l15) * 128 + h * 32 + quad * 8];
    qf[1] = *(const short8*)&q_ws[qoff +
        ((size_t)bp * 512 + n0 + 128 + l15) * 128 + h * 32 + quad * 8];
    __syncthreads();

    const unsigned short* Kb = k_ws + qoff + (size_t)bp * 512 * 128 + h * 32;
    floatx4 O0[2] = {{0.f,0.f,0.f,0.f},{0.f,0.f,0.f,0.f}};
    floatx4 O1[2] = {{0.f,0.f,0.f,0.f},{0.f,0.f,0.f,0.f}};
    float za[2][4] = {{0.f,0.f,0.f,0.f},{0.f,0.f,0.f,0.f}};
    const floatx4 zero4 = {0.f, 0.f, 0.f, 0.f};

    for (int c = 0; c < 8; ++c) {
        int mb = c * 64;
        short8 kf0 = *(const short8*)&Kb[(size_t)(mb +  0 + l15) * 128 + quad * 8];
        short8 kf1 = *(const short8*)&Kb[(size_t)(mb + 16 + l15) * 128 + quad * 8];
        short8 kf2 = *(const short8*)&Kb[(size_t)(mb + 32 + l15) * 128 + quad * 8];
        short8 kf3 = *(const short8*)&Kb[(size_t)(mb + 48 + l15) * 128 + quad * 8];

        #pragma unroll
        for (int s = 0; s < 2; ++s) {
            int ns = n0 + s * 128;
            floatx4 S[4];
            S[0] = __builtin_amdgcn_mfma_f32_16x16x32_bf16(qf[s], kf0, zero4, 0, 0, 0);
            S[1] = __builtin_amdgcn_mfma_f32_16x16x32_bf16(qf[s], kf1, zero4, 0, 0, 0);
            S[2] = __builtin_amdgcn_mfma_f32_16x16x32_bf16(qf[s], kf2, zero4, 0, 0, 0);
            S[3] = __builtin_amdgcn_mfma_f32_16x16x32_bf16(qf[s], kf3, zero4, 0, 0, 0);

            #pragma unroll
            for (int ti = 0; ti < 4; ++ti) {
                int m = mb + ti * 16 + l15;
                #pragma unroll
                for (int i = 0; i < 4; ++i) {
                    float tmv = tmt[(size_t)(ns + quad * 4 + i) * 512 + m];
                    float e = __builtin_amdgcn_exp2f(S[ti][i]);
                    za[s][i] += (tmv != 0.0f) ? e : 0.0f;
                    float w = e * tmv;
                    Ps[wv][quad * 4 + i][ti * 16 + l15] =
                        (unsigned short)((fbits(w) + 0x8000u) >> 16);
                }
            }
            #pragma unroll
            for (int kc = 0; kc < 2; ++kc) {
                short8 pa  = *(const short8*)&Ps[wv][l15][kc * 32 + quad * 8];
                short8 vb0 = *(const short8*)&Vt[l15][mb + kc * 32 + quad * 8];
                short8 vb1 = *(const short8*)&Vt[16 + l15][mb + kc * 32 + quad * 8];
                O0[s] = __builtin_amdgcn_mfma_f32_16x16x32_bf16(pa, vb0, O0[s], 0, 0, 0);
                O1[s] = __builtin_amdgcn_mfma_f32_16x16x32_bf16(pa, vb1, O1[s], 0, 0, 0);
            }
        }
    }

    #pragma unroll
    for (int s = 0; s < 2; ++s) {
        #pragma unroll
        for (int d = 1; d < 16; d <<= 1) {
            #pragma unroll
            for (int i = 0; i < 4; ++i) za[s][i] += __shfl_xor(za[s][i], d, 64);
        }
        #pragma unroll
        for (int i = 0; i < 4; ++i) {
            float rz = 1.0f / za[s][i];
            size_t row = (size_t)bp * 512 + n0 + s * 128 + quad * 4 + i;
            att_ws[row * 384 + toff + h * 32 + l15]      = f2b(O0[s][i] * rz);
            att_ws[row * 384 + toff + h * 32 + 16 + l15] = f2b(O1[s][i] * rz);
        }
    }
}

// ---------------- K3a: out-projection from pre-converted Wo (proven) ----------
__global__ __launch_bounds__(256) void k_oproj_pre(
    const unsigned short* __restrict__ att_ws,   // [32][512][384] bf16
    const unsigned short* __restrict__ Wob,      // [128][384] bf16
    const float* __restrict__ X,
    const float* __restrict__ gamma,
    const float* __restrict__ beta,
    float* __restrict__ out)
{
    int bp = blockIdx.x;
    int mt = blockIdx.y;
    __shared__ unsigned short As[64 * 128];
    __shared__ unsigned short Ws[128 * 128];
    int tid = threadIdx.x, lane = tid & 63, wv = tid >> 6;
    int l15 = lane & 15, quad = lane >> 4;

    floatx4 acc[8];
    for (int ct = 0; ct < 8; ++ct) acc[ct] = (floatx4){0.f, 0.f, 0.f, 0.f};
    size_t rowbase = (size_t)bp * 512 + mt * 64;

    for (int kc = 0; kc < 3; ++kc) {
        __syncthreads();
        for (int i = 0; i < 4; ++i) {
            int flat = i * 256 + tid;
            int row = flat >> 4, colg = (flat & 15) * 8;
            *(short8*)&As[row * 128 + colg] =
                *(const short8*)&att_ws[(rowbase + row) * 384 + kc * 128 + colg];
        }
        for (int i = 0; i < 8; ++i) {
            int flat = i * 256 + tid;
            int row = flat >> 4, colg = (flat & 15) * 8;
            *(short8*)&Ws[row * 128 + colg] =
                *(const short8*)&Wob[(size_t)row * 384 + kc * 128 + colg];
        }
        __syncthreads();
        for (int ct = 0; ct < 8; ++ct) {
            for (int kk = 0; kk < 4; ++kk) {
                short8 a = *(const short8*)&As[(wv * 16 + l15) * 128 + kk * 32 + quad * 8];
                short8 b = *(const short8*)&Ws[(ct * 16 + l15) * 128 + kk * 32 + quad * 8];
                acc[ct] = __builtin_amdgcn_mfma_f32_16x16x32_bf16(a, b, acc[ct], 0, 0, 0);
            }
        }
    }

    for (int i = 0; i < 4; ++i) {
        int lrow = wv * 16 + quad * 4 + i;
        size_t grow = rowbase + lrow;
        float vals[8];
        float s = 0.f, sq = 0.f;
        for (int ct = 0; ct < 8; ++ct) {
            int col = ct * 16 + l15;
            float v = acc[ct][i] + X[grow * 128 + col];
            vals[ct] = v;
            s += v; sq += v * v;
        }
        for (int d = 1; d < 16; d <<= 1) {
            s  += __shfl_xor(s, d, 64);
            sq += __shfl_xor(sq, d, 64);
        }
        float mu = s * (1.0f / 128.0f);
        float var = sq * (1.0f / 128.0f) - mu * mu;
        float rs = rsqrtf(var + 1e-5f);
        for (int ct = 0; ct < 8; ++ct) {
            int col = ct * 16 + l15;
            out[grow * 128 + col] = (vals[ct] - mu) * rs * gamma[col] + beta[col];
        }
    }
}

// ---------------- K3b: out-projection, inline-cvt fallback --------------------
__global__ __launch_bounds__(256) void k_oproj_cvt(
    const unsigned short* __restrict__ att_ws,
    const float* __restrict__ Wo,
    const float* __restrict__ X,
    const float* __restrict__ gamma,
    const float* __restrict__ beta,
    float* __restrict__ out)
{
    int bp = blockIdx.x;
    int mt = blockIdx.y;
    __shared__ unsigned short As[64 * 128];
    __shared__ unsigned short Ws[128 * 128];
    int tid = threadIdx.x, lane = tid & 63, wv = tid >> 6;
    int l15 = lane & 15, quad = lane >> 4;

    floatx4 acc[8];
    for (int ct = 0; ct < 8; ++ct) acc[ct] = (floatx4){0.f, 0.f, 0.f, 0.f};
    size_t rowbase = (size_t)bp * 512 + mt * 64;

    for (int kc = 0; kc < 3; ++kc) {
        __syncthreads();
        for (int i = 0; i < 4; ++i) {
            int flat = i * 256 + tid;
            int row = flat >> 4, colg = (flat & 15) * 8;
            *(short8*)&As[row * 128 + colg] =
                *(const short8*)&att_ws[(rowbase + row) * 384 + kc * 128 + colg];
        }
        for (int i = 0; i < 8; ++i) {
            int flat = i * 256 + tid;
            int row = flat >> 4, colg = (flat & 15) * 8;
            *(short8*)&Ws[row * 128 + colg] = cvt8(&Wo[(size_t)row * 384 + kc * 128 + colg]);
        }
        __syncthreads();
        for (int ct = 0; ct < 8; ++ct) {
            for (int kk = 0; kk < 4; ++kk) {
                short8 a = *(const short8*)&As[(wv * 16 + l15) * 128 + kk * 32 + quad * 8];
                short8 b = *(const short8*)&Ws[(ct * 16 + l15) * 128 + kk * 32 + quad * 8];
                acc[ct] = __builtin_amdgcn_mfma_f32_16x16x32_bf16(a, b, acc[ct], 0, 0, 0);
            }
        }
    }

    for (int i = 0; i < 4; ++i) {
        int lrow = wv * 16 + quad * 4 + i;
        size_t grow = rowbase + lrow;
        float vals[8];
        float s = 0.f, sq = 0.f;
        for (int ct = 0; ct < 8; ++ct) {
            int col = ct * 16 + l15;
            float v = acc[ct][i] + X[grow * 128 + col];
            vals[ct] = v;
            s += v; sq += v * v;
        }
        for (int d = 1; d < 16; d <<= 1) {
            s  += __shfl_xor(s, d, 64);
            sq += __shfl_xor(sq, d, 64);
        }
        float mu = s * (1.0f / 128.0f);
        float var = sq * (1.0f / 128.0f) - mu * mu;
        float rs = rsqrtf(var + 1e-5f);
        for (int ct = 0; ct < 8; ++ct) {
            int col = ct * 16 + l15;
            out[grow * 128 + col] = (vals[ct] - mu) * rs * gamma[col] + beta[col];
        }
    }
}

// ---------------- launcher ----------------
extern "C" void kernel_launch(void* const* d_in, const int* in_sizes, int n_in,
                              void* d_out, int out_size, void* d_ws, size_t ws_size,
                              hipStream_t stream) {
    const float* X     = (const float*)d_in[0];
    const float* TM    = (const float*)d_in[2];
    const float* Wq    = (const float*)d_in[3];
    const float* Wk    = (const float*)d_in[4];
    const float* Wv    = (const float*)d_in[5];
    const float* Wo    = (const float*)d_in[6];
    const float* gamma = (const float*)d_in[7];
    const float* beta  = (const float*)d_in[8];
    float* out = (float*)d_out;

    char* ws = (char*)d_ws;
    const size_t QKV1 = 2097152;             // elems per t per tensor
    const size_t QKV1B = QKV1 * 2;           // 4 MB

    if (ws_size >= WS_XL) {
        unsigned short* q3  = (unsigned short*)(ws);
        unsigned short* k3  = (unsigned short*)(ws + 3 * QKV1B);
        unsigned short* v3  = (unsigned short*)(ws + 6 * QKV1B);
        unsigned short* att = (unsigned short*)(ws + 9 * QKV1B);
        unsigned short* Wb  = (unsigned short*)(ws + 50331648ull);
        unsigned short* Wob = (unsigned short*)(ws + 50626560ull);
        k_prep_w<<<dim3(96), 256, 0, stream>>>(Wq, Wk, Wv, Wo, Wb, Wob);
        k_qkv_x<<<dim3(3, 4, 32), 256, 0, stream>>>(X, Wb, q3, k3, v3);
        k_attn2<<<dim3(2, 32, 12), 512, 0, stream>>>(q3, k3, v3, TM, att, (int)QKV1, 0);
        k_oproj_pre<<<dim3(32, 8), 256, 0, stream>>>(att, Wob, X, gamma, beta, out);
    } else if (ws_size >= WS_BIG) {
        unsigned short* q3  = (unsigned short*)(ws);
        unsigned short* k3  = (unsigned short*)(ws + 3 * QKV1B);
        unsigned short* v3  = (unsigned short*)(ws + 6 * QKV1B);
        unsigned short* att = (unsigned short*)(ws + 9 * QKV1B);
        k_qkv_cvt<<<dim3(32, 4, 3), 256, 0, stream>>>(
            X, Wq, Wk, Wv, q3, k3, v3, 16384, (int)QKV1);
        k_attn2<<<dim3(2, 32, 12), 512, 0, stream>>>(q3, k3, v3, TM, att, (int)QKV1, 0);
        k_oproj_cvt<<<dim3(32, 8), 256, 0, stream>>>(att, Wo, X, gamma, beta, out);
    } else {
        unsigned short* q_ws   = (unsigned short*)(ws);
        unsigned short* k_ws   = (unsigned short*)(ws + QKV1B);
        unsigned short* v_ws   = (unsigned short*)(ws + 2 * QKV1B);
        unsigned short* att_ws = (unsigned short*)(ws + 3 * QKV1B);
        const int tsel[3] = {0, 1, 3};
        for (int t = 0; t < 3; ++t) {
            k_qkv_cvt<<<dim3(32, 4, 1), 256, 0, stream>>>(
                X, Wq + (size_t)t * 16384, Wk + (size_t)t * 16384, Wv + (size_t)t * 16384,
                q_ws, k_ws, v_ws, 0, 0);
            k_attn2<<<dim3(2, 32, 4), 512, 0, stream>>>(
                q_ws, k_ws, v_ws, TM + (size_t)tsel[t] * 262144, att_ws, 0, t * 128);
        }
        k_oproj_cvt<<<dim3(32, 8), 256, 0, stream>>>(att_ws, Wo, X, gamma, beta, out);
    }
}